// Round 1
// baseline (325.631 us; speedup 1.0000x reference)
//
#include <hip/hip_runtime.h>
#include <float.h>

#define NBATCH 16384
// Largest magnitude that stays FINITE after fp32->bf16 RNE cast
#define SAFE_MAX 3.3e38f
#define SAFE_NEG -3.3e38f

typedef __attribute__((ext_vector_type(8))) short bf16x8;
typedef __attribute__((ext_vector_type(4))) float f32x4;

__device__ __forceinline__ float san(float v) {
    v = (v == v) ? v : 0.0f;                       // NaN -> 0
    return fminf(fmaxf(v, SAFE_NEG), SAFE_MAX);    // clamp: bf16-cast stays finite
}

__device__ __forceinline__ float tanh_fast(float a) {
    float e = __expf(a + a);
    return fmaf(-2.0f, __builtin_amdgcn_rcpf(e + 1.0f), 1.0f);
}

__device__ __forceinline__ unsigned short f2bf_rne(float v) {
    unsigned int u = __float_as_uint(v);
    return (unsigned short)((u + 0x7FFFu + ((u >> 16) & 1u)) >> 16);
}

// ==================== fused: MFMA pool + heads, one dispatch, no workspace ====
// grid 256 x 512thr (8 waves), 1 block/CU. Tile = 64 batch elements.
// Pool phase: wave w handles elements w*8..w*8+7 sequentially via the proven
// MFMA path (X in A-frag pattern, W^T staged bf16, scores via quad butterfly).
// Per-wave LDS visibility via s_waitcnt lgkmcnt(0) (wave-private buffers) so
// waves drift independently -> HBM stays saturated. z kept in LDS (stride 65).
// Heads phase: proven R6 code, pi then value sequentially on the 64-elem tile.
extern "C" __global__ void __launch_bounds__(512, 2)
fused_mfma(const float* __restrict__ X, const float* __restrict__ LM,
           const float* __restrict__ AM,
           const float* __restrict__ W, const float* __restrict__ bW,
           const float* __restrict__ vv,
           const float* __restrict__ projW, const float* __restrict__ projb,
           const float* __restrict__ piW1, const float* __restrict__ pib1,
           const float* __restrict__ piW2, const float* __restrict__ pib2,
           const float* __restrict__ piW3, const float* __restrict__ pib3,
           const float* __restrict__ vfW1, const float* __restrict__ vfb1,
           const float* __restrict__ vfW2, const float* __restrict__ vfb2,
           const float* __restrict__ vfW3, const float* __restrict__ vfb3,
           float* __restrict__ out)
{
    __shared__ __align__(16) short wt[32 * 40];   // W^T bf16 [n][k], stride 40 (2.5 KB)
    __shared__ float zl[64 * 65];                 // z[zdim][elem], stride 65 (16.6 KB)
    __shared__ float sc[8][64];                   // per-wave scores
    __shared__ float mk[8][64];                   // per-wave masks
    __shared__ float pool_s[8][32];               // per-wave pooled
    __shared__ float h1[128 * 64];                // hidden1 (32 KB)
    __shared__ float plbuf[8 * 512];              // partial logits / values (16 KB)

    const int tid  = threadIdx.x;
    const int w    = __builtin_amdgcn_readfirstlane(tid >> 6);
    const int lane = tid & 63;
    const int c    = lane & 15;
    const int quad = lane >> 4;
    const long btile = (long)blockIdx.x * 64;

    // ---- stage W^T bf16 (once per block) ----
    for (int i = tid; i < 1024; i += 512) {
        const int n = i >> 5, k = i & 31;
        wt[n * 40 + k] = (short)f2bf_rne(W[k * 32 + n]);
    }

    const float bw0 = bW[c], bw1 = bW[16 + c];
    const float vv0 = vv[c], vv1 = vv[16 + c];
    const float pjb = projb[lane];

    __syncthreads();   // wt visible

    // B-frags: lane reads Wt[n=16u+c][k=quad*8..+8] (resident for whole pool phase)
    union { bf16x8 v; uint4 q; } bfr[2];
#pragma unroll
    for (int u = 0; u < 2; ++u)
        bfr[u].q = *((const uint4*)&wt[(16 * u + c) * 40 + quad * 8]);

    // ---- preload element 0 of this wave ----
    float xr[4][8];
    float ml;
    {
        const long b = btile + w * 8;
#pragma unroll
        for (int t = 0; t < 4; ++t) {
            const float4* p = (const float4*)(X + b * 2048 + (16 * t + c) * 32 + quad * 8);
            float4 a0 = p[0], a1 = p[1];
            xr[t][0] = a0.x; xr[t][1] = a0.y; xr[t][2] = a0.z; xr[t][3] = a0.w;
            xr[t][4] = a1.x; xr[t][5] = a1.y; xr[t][6] = a1.z; xr[t][7] = a1.w;
        }
        ml = LM[b * 64 + lane];
    }

#pragma unroll 1
    for (int it = 0; it < 8; ++it) {
        const int brel = w * 8 + it;

        // prefetch next element (hides HBM latency under MFMA/softmax)
        float xn[4][8];
        float mn = 0.0f;
        if (it < 7) {
            const long bn = btile + brel + 1;
#pragma unroll
            for (int t = 0; t < 4; ++t) {
                const float4* p = (const float4*)(X + bn * 2048 + (16 * t + c) * 32 + quad * 8);
                float4 a0 = p[0], a1 = p[1];
                xn[t][0] = a0.x; xn[t][1] = a0.y; xn[t][2] = a0.z; xn[t][3] = a0.w;
                xn[t][4] = a1.x; xn[t][5] = a1.y; xn[t][6] = a1.z; xn[t][7] = a1.w;
            }
            mn = LM[bn * 64 + lane];
        }
        const bool active = ml > 0.5f;

        // pack A-frags (bf16 truncation via v_perm) — identical to proven pool path
        union { bf16x8 v; unsigned int u[4]; } afr[4];
#pragma unroll
        for (int t = 0; t < 4; ++t)
#pragma unroll
            for (int j2 = 0; j2 < 4; ++j2)
                afr[t].u[j2] = __builtin_amdgcn_perm(
                    __float_as_uint(xr[t][2 * j2 + 1]),
                    __float_as_uint(xr[t][2 * j2]), 0x07060302u);

        // 8 MFMAs: H[64 rows x 32 g]
        f32x4 acc[4][2];
#pragma unroll
        for (int t = 0; t < 4; ++t)
#pragma unroll
            for (int u = 0; u < 2; ++u) {
                acc[t][u] = (f32x4){0.f, 0.f, 0.f, 0.f};
                acc[t][u] = __builtin_amdgcn_mfma_f32_16x16x32_bf16(
                    afr[t].v, bfr[u].v, acc[t][u], 0, 0, 0);
            }

        // score[row] = sum_g tanh(H+bW)*v ; C layout row=16t+quad*4+r, col=16u+c
        mk[w][lane] = ml;
#pragma unroll
        for (int t = 0; t < 4; ++t)
#pragma unroll
            for (int r = 0; r < 4; ++r) {
                float s = tanh_fast(acc[t][0][r] + bw0) * vv0
                        + tanh_fast(acc[t][1][r] + bw1) * vv1;
                s += __shfl_xor(s, 1);
                s += __shfl_xor(s, 2);
                s += __shfl_xor(s, 4);
                s += __shfl_xor(s, 8);
                if (c == t * 4 + r)
                    sc[w][16 * t + quad * 4 + r] = s;
            }
        // wave-private buffers: drain DS queue instead of a block barrier
        asm volatile("s_waitcnt lgkmcnt(0)" ::: "memory");

        // masked softmax, lane = row
        const float s0 = sc[w][lane];
        float smx = active ? s0 : -1e30f;
#pragma unroll
        for (int off = 32; off; off >>= 1) smx = fmaxf(smx, __shfl_xor(smx, off));
        float ev = active ? __expf(s0 - smx) : 0.0f;
        float es = ev;
#pragma unroll
        for (int off = 32; off; off >>= 1) es += __shfl_xor(es, off);
        const float rcpS = __builtin_amdgcn_rcpf(es);

        float wgt[4];
#pragma unroll
        for (int t = 0; t < 4; ++t) {
            const float sr = sc[w][16 * t + c];
            const float mr = mk[w][16 * t + c];
            wgt[t] = (mr > 0.5f && es > 0.0f) ? __expf(sr - smx) * rcpS : 0.0f;
        }

        // pooled[quad*8+j] = sum_rows wgt*x
#pragma unroll
        for (int j = 0; j < 8; ++j) {
            float p = wgt[0] * xr[0][j];
#pragma unroll
            for (int t = 1; t < 4; ++t) p = fmaf(wgt[t], xr[t][j], p);
            p += __shfl_xor(p, 1);
            p += __shfl_xor(p, 2);
            p += __shfl_xor(p, 4);
            p += __shfl_xor(p, 8);
            if (c == 0) pool_s[w][quad * 8 + j] = p;
        }
        asm volatile("s_waitcnt lgkmcnt(0)" ::: "memory");

        // z[e] = pooled . projW[:,e] + projb[e]  (lane = e) -> LDS, not global
        float zv = pjb;
#pragma unroll
        for (int f = 0; f < 32; ++f)
            zv = fmaf(pool_s[w][f], projW[f * 64 + lane], zv);
        const bool any = (__ballot(active) != 0ull);
        zl[lane * 65 + brel] = any ? san(zv) : 0.0f;

        if (it < 7) {
#pragma unroll
            for (int t = 0; t < 4; ++t)
#pragma unroll
                for (int j = 0; j < 8; ++j) xr[t][j] = xn[t][j];
            ml = mn;
        }
    }
    __syncthreads();   // z tile visible to all waves

    // ==================== heads (proven R6 code, pi then value) ====================
    const int el = lane;

    // ---- pi head ----
    {
        float acc[16];
#pragma unroll
        for (int i = 0; i < 16; ++i) acc[i] = pib1[w * 16 + i];
#pragma unroll 8
        for (int e = 0; e < 64; ++e) {
            const float zv = zl[e * 65 + el];
            const float* wr = piW1 + e * 128 + w * 16;
#pragma unroll
            for (int i = 0; i < 16; ++i) acc[i] = fmaf(zv, wr[i], acc[i]);
        }
#pragma unroll
        for (int i = 0; i < 16; ++i)
            h1[(w * 16 + i) * 64 + el] = tanh_fast(acc[i]);
        __syncthreads();

        float a2[16];
#pragma unroll
        for (int i = 0; i < 16; ++i) a2[i] = pib2[w * 16 + i];
#pragma unroll 8
        for (int j = 0; j < 128; ++j) {
            const float hv = h1[j * 64 + el];
            const float* wr = piW2 + j * 128 + w * 16;
#pragma unroll
            for (int i = 0; i < 16; ++i) a2[i] = fmaf(hv, wr[i], a2[i]);
        }

        float pl[8];
#pragma unroll
        for (int a = 0; a < 8; ++a) pl[a] = 0.0f;
#pragma unroll
        for (int i = 0; i < 16; ++i) {
            const float h2 = tanh_fast(a2[i]);
            const float* wr = piW3 + (w * 16 + i) * 8;
#pragma unroll
            for (int a = 0; a < 8; ++a) pl[a] = fmaf(h2, wr[a], pl[a]);
        }
#pragma unroll
        for (int a = 0; a < 8; ++a)
            plbuf[w * 512 + el * 8 + a] = pl[a];
        __syncthreads();

        const int rel = tid >> 3, ra = tid & 7;
        float lg = pib3[ra];
#pragma unroll
        for (int w2 = 0; w2 < 8; ++w2)
            lg += plbuf[w2 * 512 + rel * 8 + ra];
        lg = san(lg);
        const long rb = btile + rel;
        const float am = AM[rb * 8 + ra];
        const bool inv = (am <= 0.0f);
        const unsigned long long bal = __ballot(inv);
        const int grp = (tid & 63) >> 3;
        const bool allinv = (((bal >> (grp * 8)) & 0xFFull) == 0xFFull);
        out[rb * 8 + ra] = allinv ? lg : (inv ? SAFE_NEG : lg);
        __syncthreads();   // plbuf/h1 safe to reuse
    }

    // ---- value head ----
    {
        float acc[16];
#pragma unroll
        for (int i = 0; i < 16; ++i) acc[i] = vfb1[w * 16 + i];
#pragma unroll 8
        for (int e = 0; e < 64; ++e) {
            const float zv = zl[e * 65 + el];
            const float* wr = vfW1 + e * 128 + w * 16;
#pragma unroll
            for (int i = 0; i < 16; ++i) acc[i] = fmaf(zv, wr[i], acc[i]);
        }
#pragma unroll
        for (int i = 0; i < 16; ++i)
            h1[(w * 16 + i) * 64 + el] = tanh_fast(acc[i]);
        __syncthreads();

        float a2[16];
#pragma unroll
        for (int i = 0; i < 16; ++i) a2[i] = vfb2[w * 16 + i];
#pragma unroll 8
        for (int j = 0; j < 128; ++j) {
            const float hv = h1[j * 64 + el];
            const float* wr = vfW2 + j * 128 + w * 16;
#pragma unroll
            for (int i = 0; i < 16; ++i) a2[i] = fmaf(hv, wr[i], a2[i]);
        }
        float pv = 0.0f;
#pragma unroll
        for (int i = 0; i < 16; ++i)
            pv = fmaf(tanh_fast(a2[i]), vfW3[w * 16 + i], pv);
        plbuf[el * 8 + w] = pv;
        __syncthreads();

        if (tid < 64) {
            float val = vfb3[0];
#pragma unroll
            for (int w2 = 0; w2 < 8; ++w2) val += plbuf[tid * 8 + w2];
            out[(long)NBATCH * 8 + btile + tid] = san(val);
        }
    }
}

// ==================== split kernels kept compiled for cheap revert ====================
extern "C" __global__ void __launch_bounds__(256, 4)
pool_kernel(const float* __restrict__ X, const float* __restrict__ LM,
            const float* __restrict__ W, const float* __restrict__ bW,
            const float* __restrict__ vv,
            const float* __restrict__ projW, const float* __restrict__ projb,
            float* __restrict__ zout)
{
    __shared__ __align__(16) short wt[32 * 40];
    __shared__ float sc[4][64];
    __shared__ float mk[4][64];
    __shared__ float pool_s[4][32];

    const int tid  = threadIdx.x;
    const int w    = __builtin_amdgcn_readfirstlane(tid >> 6);
    const int lane = tid & 63;
    const int c    = lane & 15;
    const int quad = lane >> 4;
    const long b   = (long)blockIdx.x * 4 + w;

    for (int i = tid; i < 1024; i += 256) {
        const int n = i >> 5, k = i & 31;
        wt[n * 40 + k] = (short)f2bf_rne(W[k * 32 + n]);
    }

    float xr[4][8];
#pragma unroll
    for (int t = 0; t < 4; ++t) {
        const float4* p = (const float4*)(X + b * 2048 + (16 * t + c) * 32 + quad * 8);
        float4 a0 = p[0], a1 = p[1];
        xr[t][0] = a0.x; xr[t][1] = a0.y; xr[t][2] = a0.z; xr[t][3] = a0.w;
        xr[t][4] = a1.x; xr[t][5] = a1.y; xr[t][6] = a1.z; xr[t][7] = a1.w;
    }
    const float ml = LM[b * 64 + lane];
    const bool active = ml > 0.5f;

    union { bf16x8 v; unsigned int u[4]; } afr[4];
#pragma unroll
    for (int t = 0; t < 4; ++t)
#pragma unroll
        for (int j2 = 0; j2 < 4; ++j2)
            afr[t].u[j2] = __builtin_amdgcn_perm(
                __float_as_uint(xr[t][2 * j2 + 1]),
                __float_as_uint(xr[t][2 * j2]), 0x07060302u);

    __syncthreads();

    union { bf16x8 v; uint4 q; } bfr[2];
#pragma unroll
    for (int u = 0; u < 2; ++u)
        bfr[u].q = *((const uint4*)&wt[(16 * u + c) * 40 + quad * 8]);

    f32x4 acc[4][2];
#pragma unroll
    for (int t = 0; t < 4; ++t)
#pragma unroll
        for (int u = 0; u < 2; ++u) {
            acc[t][u] = (f32x4){0.f, 0.f, 0.f, 0.f};
            acc[t][u] = __builtin_amdgcn_mfma_f32_16x16x32_bf16(
                afr[t].v, bfr[u].v, acc[t][u], 0, 0, 0);
        }

    const float bw0 = bW[c], bw1 = bW[16 + c];
    const float vv0 = vv[c], vv1 = vv[16 + c];
    mk[w][lane] = ml;
#pragma unroll
    for (int t = 0; t < 4; ++t)
#pragma unroll
        for (int r = 0; r < 4; ++r) {
            float s = tanh_fast(acc[t][0][r] + bw0) * vv0
                    + tanh_fast(acc[t][1][r] + bw1) * vv1;
            s += __shfl_xor(s, 1);
            s += __shfl_xor(s, 2);
            s += __shfl_xor(s, 4);
            s += __shfl_xor(s, 8);
            if (c == t * 4 + r)
                sc[w][16 * t + quad * 4 + r] = s;
        }
    __syncthreads();

    const float s0 = sc[w][lane];
    float smx = active ? s0 : -1e30f;
#pragma unroll
    for (int off = 32; off; off >>= 1) smx = fmaxf(smx, __shfl_xor(smx, off));
    float ev = active ? __expf(s0 - smx) : 0.0f;
    float es = ev;
#pragma unroll
    for (int off = 32; off; off >>= 1) es += __shfl_xor(es, off);
    const float rcpS = __builtin_amdgcn_rcpf(es);

    float wgt[4];
#pragma unroll
    for (int t = 0; t < 4; ++t) {
        const float sr = sc[w][16 * t + c];
        const float mr = mk[w][16 * t + c];
        wgt[t] = (mr > 0.5f && es > 0.0f) ? __expf(sr - smx) * rcpS : 0.0f;
    }

#pragma unroll
    for (int j = 0; j < 8; ++j) {
        float p = wgt[0] * xr[0][j];
#pragma unroll
        for (int t = 1; t < 4; ++t) p = fmaf(wgt[t], xr[t][j], p);
        p += __shfl_xor(p, 1);
        p += __shfl_xor(p, 2);
        p += __shfl_xor(p, 4);
        p += __shfl_xor(p, 8);
        if (c == 0) pool_s[w][quad * 8 + j] = p;
    }
    __syncthreads();

    float zv = projb[lane];
#pragma unroll
    for (int f = 0; f < 32; ++f)
        zv = fmaf(pool_s[w][f], projW[f * 64 + lane], zv);
    const bool any = (__ballot(active) != 0ull);
    zout[b * 64 + lane] = any ? san(zv) : 0.0f;
}

#define ZT 0
#define H1 4160
#define PL 0
extern "C" __global__ void __launch_bounds__(512)
heads_kernel(const float* __restrict__ z, const float* __restrict__ AM,
             const float* __restrict__ piW1, const float* __restrict__ pib1,
             const float* __restrict__ piW2, const float* __restrict__ pib2,
             const float* __restrict__ piW3, const float* __restrict__ pib3,
             const float* __restrict__ vfW1, const float* __restrict__ vfb1,
             const float* __restrict__ vfW2, const float* __restrict__ vfb2,
             const float* __restrict__ vfW3, const float* __restrict__ vfb3,
             float* __restrict__ out)
{
    __shared__ float smem[12352];

    const int tid  = threadIdx.x;
    const int w    = __builtin_amdgcn_readfirstlane(tid >> 6);
    const int el   = tid & 63;
    const bool isPi = (blockIdx.x & 1) == 0;
    const int tile  = blockIdx.x >> 1;

    for (int i = tid; i < 4096; i += 512)
        smem[ZT + (i >> 6) * 65 + (i & 63)] = z[(long)tile * 4096 + i];
    __syncthreads();

    const float* W1 = isPi ? piW1 : vfW1;
    const float* b1 = isPi ? pib1 : vfb1;
    const float* W2 = isPi ? piW2 : vfW2;
    const float* b2 = isPi ? pib2 : vfb2;

    float acc[16];
#pragma unroll
    for (int i = 0; i < 16; ++i) acc[i] = b1[w * 16 + i];
#pragma unroll 8
    for (int e = 0; e < 64; ++e) {
        const float zv = smem[ZT + el * 65 + e];
        const float* wr = W1 + e * 128 + w * 16;
#pragma unroll
        for (int i = 0; i < 16; ++i) acc[i] = fmaf(zv, wr[i], acc[i]);
    }
#pragma unroll
    for (int i = 0; i < 16; ++i)
        smem[H1 + (w * 16 + i) * 64 + el] = tanh_fast(acc[i]);
    __syncthreads();

    float a2[16];
#pragma unroll
    for (int i = 0; i < 16; ++i) a2[i] = b2[w * 16 + i];
#pragma unroll 8
    for (int j = 0; j < 128; ++j) {
        const float hv = smem[H1 + j * 64 + el];
        const float* wr = W2 + j * 128 + w * 16;
#pragma unroll
        for (int i = 0; i < 16; ++i) a2[i] = fmaf(hv, wr[i], a2[i]);
    }

    if (isPi) {
        float pl[8];
#pragma unroll
        for (int a = 0; a < 8; ++a) pl[a] = 0.0f;
#pragma unroll
        for (int i = 0; i < 16; ++i) {
            const float h2 = tanh_fast(a2[i]);
            const float* wr = piW3 + (w * 16 + i) * 8;
#pragma unroll
            for (int a = 0; a < 8; ++a) pl[a] = fmaf(h2, wr[a], pl[a]);
        }
#pragma unroll
        for (int a = 0; a < 8; ++a)
            smem[PL + w * 512 + el * 8 + a] = pl[a];
        __syncthreads();

        const int rel = tid >> 3, ra = tid & 7;
        float lg = pib3[ra];
#pragma unroll
        for (int w2 = 0; w2 < 8; ++w2)
            lg += smem[PL + w2 * 512 + rel * 8 + ra];
        lg = san(lg);
        const long rb = (long)tile * 64 + rel;
        const float am = AM[rb * 8 + ra];
        const bool inv = (am <= 0.0f);
        const unsigned long long bal = __ballot(inv);
        const int grp = (tid & 63) >> 3;
        const bool allinv = (((bal >> (grp * 8)) & 0xFFull) == 0xFFull);
        out[rb * 8 + ra] = allinv ? lg : (inv ? SAFE_NEG : lg);
    } else {
        float pv = 0.0f;
#pragma unroll
        for (int i = 0; i < 16; ++i)
            pv = fmaf(tanh_fast(a2[i]), vfW3[w * 16 + i], pv);
        smem[PL + el * 8 + w] = pv;
        __syncthreads();

        if (tid < 64) {
            float val = vfb3[0];
#pragma unroll
            for (int w2 = 0; w2 < 8; ++w2) val += smem[PL + tid * 8 + w2];
            out[(long)NBATCH * 8 + (long)tile * 64 + tid] = san(val);
        }
    }
}

// ---------------- launcher ----------------
extern "C" void kernel_launch(void* const* d_in, const int* in_sizes, int n_in,
                              void* d_out, int out_size, void* d_ws, size_t ws_size,
                              hipStream_t stream) {
    const float* X     = (const float*)d_in[0];
    const float* LM    = (const float*)d_in[1];
    const float* AM    = (const float*)d_in[2];
    const float* W     = (const float*)d_in[3];
    const float* bW    = (const float*)d_in[4];
    const float* vv    = (const float*)d_in[5];
    const float* projW = (const float*)d_in[6];
    const float* projb = (const float*)d_in[7];
    const float* piW1  = (const float*)d_in[8];
    const float* pib1  = (const float*)d_in[9];
    const float* piW2  = (const float*)d_in[10];
    const float* pib2  = (const float*)d_in[11];
    const float* piW3  = (const float*)d_in[12];
    const float* pib3  = (const float*)d_in[13];
    const float* vfW1  = (const float*)d_in[14];
    const float* vfb1  = (const float*)d_in[15];
    const float* vfW2  = (const float*)d_in[16];
    const float* vfb2  = (const float*)d_in[17];
    const float* vfW3  = (const float*)d_in[18];
    const float* vfb3  = (const float*)d_in[19];

    float* outp = (float*)d_out;

    // Single fused dispatch: no workspace, no inter-kernel drain, no z round-trip.
    fused_mfma<<<NBATCH / 64, 512, 0, stream>>>(
        X, LM, AM, W, bW, vv, projW, projb,
        piW1, pib1, piW2, pib2, piW3, pib3,
        vfW1, vfb1, vfW2, vfb2, vfW3, vfb3, outp);
}

// Round 2
// 318.839 us; speedup vs baseline: 1.0213x; 1.0213x over previous
//
#include <hip/hip_runtime.h>
#include <float.h>

#define NBATCH 16384
// Largest magnitude that stays FINITE after fp32->bf16 RNE cast
#define SAFE_MAX 3.3e38f
#define SAFE_NEG -3.3e38f

typedef __attribute__((ext_vector_type(8))) short bf16x8;
typedef __attribute__((ext_vector_type(4))) float f32x4;

__device__ __forceinline__ float san(float v) {
    v = (v == v) ? v : 0.0f;                       // NaN -> 0
    return fminf(fmaxf(v, SAFE_NEG), SAFE_MAX);    // clamp: bf16-cast stays finite
}

__device__ __forceinline__ float tanh_fast(float a) {
    float e = __expf(a + a);
    return fmaf(-2.0f, __builtin_amdgcn_rcpf(e + 1.0f), 1.0f);
}

__device__ __forceinline__ unsigned short f2bf_rne(float v) {
    unsigned int u = __float_as_uint(v);
    return (unsigned short)((u + 0x7FFFu + ((u >> 16) & 1u)) >> 16);
}

// ==================== fused v2: swapped-MFMA pool + concurrent heads =========
// grid 256 x 1024thr (16 waves), 1 block/CU -> 16 waves/CU during pool.
// Pool: wave w owns elements w*4..w*4+3. Swapped MFMA D = W^T X^T = H^T puts
// H[.,l] in the REGISTER index of lane (l = 16t + c): score reduce = 8 reg-FMA
// + 2 shuffles; softmax fully in registers (8 shuffles, zero LDS round-trips).
// Weights land in the lane owning xr[t][.], so the proven pooled/z-proj path
// is unchanged. Heads: pi on waves 0-7, value on waves 8-15, concurrent.
extern "C" __global__ void __launch_bounds__(1024, 4)
fused_v2(const float* __restrict__ X, const float* __restrict__ LM,
         const float* __restrict__ AM,
         const float* __restrict__ W, const float* __restrict__ bW,
         const float* __restrict__ vv,
         const float* __restrict__ projW, const float* __restrict__ projb,
         const float* __restrict__ piW1, const float* __restrict__ pib1,
         const float* __restrict__ piW2, const float* __restrict__ pib2,
         const float* __restrict__ piW3, const float* __restrict__ pib3,
         const float* __restrict__ vfW1, const float* __restrict__ vfb1,
         const float* __restrict__ vfW2, const float* __restrict__ vfb2,
         const float* __restrict__ vfW3, const float* __restrict__ vfb3,
         float* __restrict__ out)
{
    __shared__ __align__(16) short wt[32 * 40];   // W^T bf16 [n=g][k=f], stride 40
    __shared__ float zl[64 * 65];                 // z[zdim][elem], stride 65
    __shared__ float pool_s[16][32];              // per-wave pooled
    __shared__ float h1pi[128 * 64];              // pi hidden1 (32 KB)
    __shared__ float h1v[128 * 64];               // value hidden1 (32 KB)
    __shared__ float plpi[8 * 512];               // pi partial logits (16 KB)
    __shared__ float plv[64 * 8];                 // value partials (2 KB)

    const int tid  = threadIdx.x;
    const int w    = __builtin_amdgcn_readfirstlane(tid >> 6);
    const int lane = tid & 63;
    const int c    = lane & 15;
    const int quad = lane >> 4;
    const long btile = (long)blockIdx.x * 64;

    // ---- stage W^T bf16 (1024 threads, one element each) ----
    {
        const int n = tid >> 5, k = tid & 31;
        wt[n * 40 + k] = (short)f2bf_rne(W[k * 32 + n]);
    }

    // per-lane bias/v for g = 16u + 4*quad + r  (register-resident)
    float bwr[8], vvr[8];
#pragma unroll
    for (int u = 0; u < 2; ++u)
#pragma unroll
        for (int r = 0; r < 4; ++r) {
            const int g = 16 * u + 4 * quad + r;
            bwr[u * 4 + r] = bW[g];
            vvr[u * 4 + r] = vv[g];
        }
    const float pjb = projb[lane];

    __syncthreads();   // wt visible

    // W^T A-frags: lane holds A[m=g=16u+c][k=quad*8..+8] (resident all pool)
    union { bf16x8 v; uint4 q; } bfr[2];
#pragma unroll
    for (int u = 0; u < 2; ++u)
        bfr[u].q = *((const uint4*)&wt[(16 * u + c) * 40 + quad * 8]);

    // ==================== pool phase: 4 elements per wave ====================
#pragma unroll 1
    for (int it = 0; it < 4; ++it) {
        const int brel = w * 4 + it;
        const long b = btile + brel;

        // X rows l=16t+c, k-slice quad*8..+8 (fp32 kept for pooling)
        float xr[4][8];
#pragma unroll
        for (int t = 0; t < 4; ++t) {
            const float4* p = (const float4*)(X + b * 2048 + (16 * t + c) * 32 + quad * 8);
            float4 a0 = p[0], a1 = p[1];
            xr[t][0] = a0.x; xr[t][1] = a0.y; xr[t][2] = a0.z; xr[t][3] = a0.w;
            xr[t][4] = a1.x; xr[t][5] = a1.y; xr[t][6] = a1.z; xr[t][7] = a1.w;
        }
        // masks for this lane's 4 rows l = 16t+c
        float ml[4];
#pragma unroll
        for (int t = 0; t < 4; ++t) ml[t] = LM[b * 64 + 16 * t + c];

        // pack X B-frags (bf16 truncation via v_perm — proven pack)
        union { bf16x8 v; unsigned int u[4]; } afr[4];
#pragma unroll
        for (int t = 0; t < 4; ++t)
#pragma unroll
            for (int j2 = 0; j2 < 4; ++j2)
                afr[t].u[j2] = __builtin_amdgcn_perm(
                    __float_as_uint(xr[t][2 * j2 + 1]),
                    __float_as_uint(xr[t][2 * j2]), 0x07060302u);

        // swapped MFMA: D[g,l] = sum_f W[f,g] X[l,f]; u-tiles sequential to
        // keep register peak low. sp[t] = per-lane score partial for l=16t+c.
        float sp[4] = {0.f, 0.f, 0.f, 0.f};
#pragma unroll
        for (int u = 0; u < 2; ++u) {
            f32x4 a[4];
#pragma unroll
            for (int t = 0; t < 4; ++t) {
                a[t] = (f32x4){0.f, 0.f, 0.f, 0.f};
                a[t] = __builtin_amdgcn_mfma_f32_16x16x32_bf16(
                    bfr[u].v, afr[t].v, a[t], 0, 0, 0);
            }
#pragma unroll
            for (int t = 0; t < 4; ++t)
#pragma unroll
                for (int r = 0; r < 4; ++r)
                    sp[t] = fmaf(tanh_fast(a[t][r] + bwr[u * 4 + r]),
                                 vvr[u * 4 + r], sp[t]);
        }

        // quad butterfly: all lanes get full score for their l=16t+c
        float s[4];
#pragma unroll
        for (int t = 0; t < 4; ++t) {
            float v0 = sp[t];
            v0 += __shfl_xor(v0, 16);
            v0 += __shfl_xor(v0, 32);
            s[t] = v0;
        }

        // in-register masked softmax over all 64 rows
        bool act[4];
#pragma unroll
        for (int t = 0; t < 4; ++t) act[t] = ml[t] > 0.5f;

        float m = -1e30f;
#pragma unroll
        for (int t = 0; t < 4; ++t) m = fmaxf(m, act[t] ? s[t] : -1e30f);
        m = fmaxf(m, __shfl_xor(m, 1));
        m = fmaxf(m, __shfl_xor(m, 2));
        m = fmaxf(m, __shfl_xor(m, 4));
        m = fmaxf(m, __shfl_xor(m, 8));

        float ev[4];
        float es = 0.0f;
#pragma unroll
        for (int t = 0; t < 4; ++t) {
            ev[t] = act[t] ? __expf(s[t] - m) : 0.0f;
            es += ev[t];
        }
        es += __shfl_xor(es, 1);
        es += __shfl_xor(es, 2);
        es += __shfl_xor(es, 4);
        es += __shfl_xor(es, 8);
        const float rcpS = __builtin_amdgcn_rcpf(es);

        float wgt[4];
#pragma unroll
        for (int t = 0; t < 4; ++t)
            wgt[t] = (act[t] && es > 0.0f) ? ev[t] * rcpS : 0.0f;

        // pooled[quad*8+j] = sum_l wgt[l]*X[l,f] : 4 FMA + c-butterfly per j
#pragma unroll
        for (int j = 0; j < 8; ++j) {
            float p = wgt[0] * xr[0][j];
#pragma unroll
            for (int t = 1; t < 4; ++t) p = fmaf(wgt[t], xr[t][j], p);
            p += __shfl_xor(p, 1);
            p += __shfl_xor(p, 2);
            p += __shfl_xor(p, 4);
            p += __shfl_xor(p, 8);
            if (c == 0) pool_s[w][quad * 8 + j] = p;
        }
        // wave-private buffer: drain DS queue (no block barrier needed)
        asm volatile("s_waitcnt lgkmcnt(0)" ::: "memory");

        // z[e] = pooled . projW[:,e] + projb[e]  (lane = e) -> LDS
        float zv = pjb;
#pragma unroll
        for (int f = 0; f < 32; ++f)
            zv = fmaf(pool_s[w][f], projW[f * 64 + lane], zv);
        const bool anyl = act[0] | act[1] | act[2] | act[3];
        const bool any = (__ballot(anyl) != 0ull);
        zl[lane * 65 + brel] = any ? san(zv) : 0.0f;
    }
    __syncthreads();   // z tile visible to all waves

    // ==================== heads: pi on waves 0-7, value on waves 8-15 ========
    const int el = lane;
    const int w8 = w - 8;

    // ---- phase 1: layer 1 ----
    if (w < 8) {
        float acc[16];
#pragma unroll
        for (int i = 0; i < 16; ++i) acc[i] = pib1[w * 16 + i];
#pragma unroll 8
        for (int e = 0; e < 64; ++e) {
            const float zv = zl[e * 65 + el];
            const float* wr = piW1 + e * 128 + w * 16;
#pragma unroll
            for (int i = 0; i < 16; ++i) acc[i] = fmaf(zv, wr[i], acc[i]);
        }
#pragma unroll
        for (int i = 0; i < 16; ++i)
            h1pi[(w * 16 + i) * 64 + el] = tanh_fast(acc[i]);
    } else {
        float acc[16];
#pragma unroll
        for (int i = 0; i < 16; ++i) acc[i] = vfb1[w8 * 16 + i];
#pragma unroll 8
        for (int e = 0; e < 64; ++e) {
            const float zv = zl[e * 65 + el];
            const float* wr = vfW1 + e * 128 + w8 * 16;
#pragma unroll
            for (int i = 0; i < 16; ++i) acc[i] = fmaf(zv, wr[i], acc[i]);
        }
#pragma unroll
        for (int i = 0; i < 16; ++i)
            h1v[(w8 * 16 + i) * 64 + el] = tanh_fast(acc[i]);
    }
    __syncthreads();

    // ---- phase 2: layer 2 + layer 3 partials ----
    if (w < 8) {
        float a2[16];
#pragma unroll
        for (int i = 0; i < 16; ++i) a2[i] = pib2[w * 16 + i];
#pragma unroll 8
        for (int j = 0; j < 128; ++j) {
            const float hv = h1pi[j * 64 + el];
            const float* wr = piW2 + j * 128 + w * 16;
#pragma unroll
            for (int i = 0; i < 16; ++i) a2[i] = fmaf(hv, wr[i], a2[i]);
        }
        float pl[8];
#pragma unroll
        for (int a = 0; a < 8; ++a) pl[a] = 0.0f;
#pragma unroll
        for (int i = 0; i < 16; ++i) {
            const float h2 = tanh_fast(a2[i]);
            const float* wr = piW3 + (w * 16 + i) * 8;
#pragma unroll
            for (int a = 0; a < 8; ++a) pl[a] = fmaf(h2, wr[a], pl[a]);
        }
#pragma unroll
        for (int a = 0; a < 8; ++a)
            plpi[w * 512 + el * 8 + a] = pl[a];
    } else {
        float a2[16];
#pragma unroll
        for (int i = 0; i < 16; ++i) a2[i] = vfb2[w8 * 16 + i];
#pragma unroll 8
        for (int j = 0; j < 128; ++j) {
            const float hv = h1v[j * 64 + el];
            const float* wr = vfW2 + j * 128 + w8 * 16;
#pragma unroll
            for (int i = 0; i < 16; ++i) a2[i] = fmaf(hv, wr[i], a2[i]);
        }
        float pv = 0.0f;
#pragma unroll
        for (int i = 0; i < 16; ++i)
            pv = fmaf(tanh_fast(a2[i]), vfW3[w8 * 16 + i], pv);
        plv[el * 8 + w8] = pv;
    }
    __syncthreads();

    // ---- phase 3: final reductions + stores ----
    if (w < 8) {
        // tid in [0,512): rel = element in tile, ra = action
        const int rel = tid >> 3, ra = tid & 7;
        float lg = pib3[ra];
#pragma unroll
        for (int w2 = 0; w2 < 8; ++w2)
            lg += plpi[w2 * 512 + rel * 8 + ra];
        lg = san(lg);
        const long rb = btile + rel;
        const float am = AM[rb * 8 + ra];
        const bool inv = (am <= 0.0f);
        const unsigned long long bal = __ballot(inv);
        const int grp = (tid & 63) >> 3;
        const bool allinv = (((bal >> (grp * 8)) & 0xFFull) == 0xFFull);
        out[rb * 8 + ra] = allinv ? lg : (inv ? SAFE_NEG : lg);
    } else if (w == 8) {
        float val = vfb3[0];
#pragma unroll
        for (int w2 = 0; w2 < 8; ++w2) val += plv[lane * 8 + w2];
        out[(long)NBATCH * 8 + btile + lane] = san(val);
    }
}

// ---------------- launcher ----------------
extern "C" void kernel_launch(void* const* d_in, const int* in_sizes, int n_in,
                              void* d_out, int out_size, void* d_ws, size_t ws_size,
                              hipStream_t stream) {
    const float* X     = (const float*)d_in[0];
    const float* LM    = (const float*)d_in[1];
    const float* AM    = (const float*)d_in[2];
    const float* W     = (const float*)d_in[3];
    const float* bW    = (const float*)d_in[4];
    const float* vv    = (const float*)d_in[5];
    const float* projW = (const float*)d_in[6];
    const float* projb = (const float*)d_in[7];
    const float* piW1  = (const float*)d_in[8];
    const float* pib1  = (const float*)d_in[9];
    const float* piW2  = (const float*)d_in[10];
    const float* pib2  = (const float*)d_in[11];
    const float* piW3  = (const float*)d_in[12];
    const float* pib3  = (const float*)d_in[13];
    const float* vfW1  = (const float*)d_in[14];
    const float* vfb1  = (const float*)d_in[15];
    const float* vfW2  = (const float*)d_in[16];
    const float* vfb2  = (const float*)d_in[17];
    const float* vfW3  = (const float*)d_in[18];
    const float* vfb3  = (const float*)d_in[19];

    float* outp = (float*)d_out;

    fused_v2<<<NBATCH / 64, 1024, 0, stream>>>(
        X, LM, AM, W, bW, vv, projW, projb,
        piW1, pib1, piW2, pib2, piW3, pib3,
        vfW1, vfb1, vfW2, vfb2, vfW3, vfb3, outp);
}